// Round 6
// baseline (194.285 us; speedup 1.0000x reference)
//
#include <hip/hip_runtime.h>
#include <math.h>

#define D_FEAT 100
#define QUARTER 25         // active lanes per 32-lane half: lane l holds elems 4l..4l+3
#define ROW_STRIDE 300     // 3 * D_FEAT concatenated output blocks
#define MAXE_LDS 64        // (col,w) slots per node staged in LDS

// ---------------------------------------------------------------------------
// fast tanh via hardware exp (safe: |2x| <= ~11 for all our inputs)
// ---------------------------------------------------------------------------
__device__ __forceinline__ float fast_tanh(float x) {
    float ax = fabsf(x);
    float e  = __expf(2.f * ax);
    float t  = 1.f - 2.f / (e + 1.f);
    return copysignf(t, x);
}

// ---------------------------------------------------------------------------
// bf16 packing (RNE)
// ---------------------------------------------------------------------------
__device__ __forceinline__ unsigned pack_bf16x2(float a, float b) {
    unsigned ua = __float_as_uint(a);
    unsigned ub = __float_as_uint(b);
    ua += 0x7fffu + ((ua >> 16) & 1u);
    ub += 0x7fffu + ((ub >> 16) & 1u);
    return (ua >> 16) | (ub & 0xffff0000u);
}
__device__ __forceinline__ unsigned long long pack_bf16x4(float a, float b,
                                                          float c, float d) {
    return (unsigned long long)pack_bf16x2(a, b) |
           ((unsigned long long)pack_bf16x2(c, d) << 32);
}

// gather 4 feature elements of `col` (bf16x4 packed table or f32 stride-300)
template <bool BF16>
__device__ __forceinline__ void gather4(const void* __restrict__ prev, int col,
                                        int l, bool act,
                                        float& x0, float& x1, float& x2, float& x3) {
    x0 = x1 = x2 = x3 = 0.f;
    if (!act) return;
    if (BF16) {
        unsigned long long u =
            ((const unsigned long long*)prev)[(size_t)(unsigned)(col * QUARTER + l)];
        unsigned lo = (unsigned)u, hi = (unsigned)(u >> 32);
        x0 = __uint_as_float(lo << 16);
        x1 = __uint_as_float(lo & 0xffff0000u);
        x2 = __uint_as_float(hi << 16);
        x3 = __uint_as_float(hi & 0xffff0000u);
    } else {
        float4 v = ((const float4*)((const float*)prev + (size_t)col * ROW_STRIDE))[l];
        x0 = v.x; x1 = v.y; x2 = v.z; x3 = v.w;
    }
}

// butterfly sum within each 32-lane half
__device__ __forceinline__ float half_reduce(float v) {
    #pragma unroll
    for (int off = 16; off; off >>= 1) v += __shfl_xor(v, off, 64);
    return v;
}

// ---------------------------------------------------------------------------
// Kernel 1: 2 nodes per wave (one per half).
// ---------------------------------------------------------------------------
__global__ __launch_bounds__(256) void tanh_score_kernel(
    const float* __restrict__ features,
    float* __restrict__ out,
    unsigned long long* __restrict__ ftab0,
    float* __restrict__ escore0,
    const float* __restrict__ none_rel,
    int N)
{
    int waveId = (int)((blockIdx.x * blockDim.x + threadIdx.x) >> 6);
    int lane = threadIdx.x & 63;
    int half = lane >> 5;
    int l    = lane & 31;
    int n    = waveId * 2 + half;
    const bool valid_n = (n < N);
    const bool act = valid_n && (l < QUARTER);

    float x0 = 0.f, x1 = 0.f, x2 = 0.f, x3 = 0.f;
    if (act) {
        float4 f = ((const float4*)(features + (size_t)n * D_FEAT))[l];
        x0 = fast_tanh(f.x); x1 = fast_tanh(f.y);
        x2 = fast_tanh(f.z); x3 = fast_tanh(f.w);
        ((float4*)(out + (size_t)n * ROW_STRIDE))[l] = make_float4(x0, x1, x2, x3);
        if (ftab0) ftab0[(size_t)n * QUARTER + l] = pack_bf16x4(x0, x1, x2, x3);
    }

    float nx = 0.f, ny = 0.f, nz = 0.f, nw = 0.f;
    if (l < QUARTER) {
        float4 v = ((const float4*)none_rel)[l];
        nx = v.x; ny = v.y; nz = v.z; nw = v.w;
    }
    float ss = half_reduce(nx * nx + ny * ny + nz * nz + nw * nw);
    float inv_nr = 1.f / fmaxf(sqrtf(ss), 1e-12f);

    float dot = half_reduce(x0 * nx + x1 * ny + x2 * nz + x3 * nw) * inv_nr;
    float sq  = half_reduce(x0 * x0 + x1 * x1 + x2 * x2 + x3 * x3);
    if (l == 0 && valid_n)
        escore0[n] = __expf(-dot / fmaxf(sqrtf(sq), 1e-12f));
}

// ---------------------------------------------------------------------------
// Kernel 2: CSR row offsets via binary search (rows are sorted).
// ---------------------------------------------------------------------------
__global__ void csr_kernel(const int* __restrict__ adj, int E,
                           int* __restrict__ start, int N) {
    int n = blockIdx.x * blockDim.x + threadIdx.x;
    if (n > N) return;
    if (n == N) { start[N] = E; return; }
    int lo = 0, hi = E;
    while (lo < hi) {
        int mid = (lo + hi) >> 1;
        if (adj[2 * mid] < n) lo = mid + 1; else hi = mid;
    }
    start[n] = lo;
}

// ---------------------------------------------------------------------------
// Kernel 3: fused attention layer, 2 nodes per wave.
//  Stage all (col, w) pairs of both nodes into LDS (zero-padded to 64 slots).
//  Aggregate in wave-uniform rounds of 8 edges/half: one ds_read_b64 broadcast
//  + one 8B bf16x4 gather per lane per edge; padded slots gather row 0 (L1-hot)
//  with w=0. Denominator division deferred to the epilogue.
// ---------------------------------------------------------------------------
template <bool BF16>
__global__ __launch_bounds__(256) void attn_kernel(
    const void* __restrict__ prev,
    float* __restrict__ outp,
    unsigned long long* __restrict__ ftab_out,
    const int2* __restrict__ adj2,
    const int* __restrict__ start,
    const float* __restrict__ escore_in,
    float* __restrict__ escore_out,
    const float* __restrict__ none_rel,
    int N)
{
    __shared__ int2 cw_lds[4][2 * MAXE_LDS];   // [wave_in_block][half*64 + slot]

    int tid  = threadIdx.x;
    int wib  = tid >> 6;
    int lane = tid & 63;
    int half = lane >> 5;
    int l    = lane & 31;
    int n    = ((int)blockIdx.x * 4 + wib) * 2 + half;
    const bool valid_n = (n < N);
    const bool act = valid_n && (l < QUARTER);

    int e0 = 0, e1 = 0;
    if (valid_n) { e0 = start[n]; e1 = start[n + 1]; }
    const int deg = e1 - e0;

    // ---- stage (col, w) into LDS; accumulate denominator ----
    int2* slots = &cw_lds[wib][half * MAXE_LDS];
    int   c0 = 0, c1 = 0;
    float w0 = 0.f, w1 = 0.f;
    if (l < deg)      { c0 = adj2[e0 + l].y;      w0 = escore_in[c0]; }
    if (l + 32 < deg) { c1 = adj2[e0 + l + 32].y; w1 = escore_in[c1]; }
    slots[l]      = make_int2(c0, __float_as_int(w0));
    slots[l + 32] = make_int2(c1, __float_as_int(w1));
    float d_l = w0 + w1;
    for (int e = e0 + MAXE_LDS + l; e < e1; e += 32)   // deg > 64: ~never
        d_l += escore_in[adj2[e].y];
    d_l = half_reduce(d_l);
    const float inv_d = (deg > 0) ? 1.f / d_l : 0.f;

    // ---- aggregation: wave-uniform rounds of 8 ----
    int maxdeg = deg;
    { int o = __shfl_xor(maxdeg, 32, 64); maxdeg = maxdeg > o ? maxdeg : o; }
    const int cap = maxdeg < MAXE_LDS ? maxdeg : MAXE_LDS;

    float a0 = 0.f, a1 = 0.f, a2 = 0.f, a3 = 0.f;
    for (int r = 0; r < cap; r += 8) {
        #pragma unroll
        for (int j = 0; j < 8; ++j) {
            int2 cw = slots[r + j];                    // half-uniform broadcast
            float w = __int_as_float(cw.y);
            float p0, p1, p2, p3;
            gather4<BF16>(prev, cw.x, l, act, p0, p1, p2, p3);
            a0 += w * p0; a1 += w * p1; a2 += w * p2; a3 += w * p3;
        }
    }
    for (int e = e0 + MAXE_LDS; e < e1; ++e) {         // deg > 64: ~never
        int   c = adj2[e].y;
        float w = escore_in[c];
        float p0, p1, p2, p3;
        gather4<BF16>(prev, c, l, act, p0, p1, p2, p3);
        a0 += w * p0; a1 += w * p1; a2 += w * p2; a3 += w * p3;
    }

    float r0 = fast_tanh(a0 * inv_d);
    float r1 = fast_tanh(a1 * inv_d);
    float r2 = fast_tanh(a2 * inv_d);
    float r3 = fast_tanh(a3 * inv_d);
    if (act) {
        ((float4*)(outp + (size_t)n * ROW_STRIDE))[l] = make_float4(r0, r1, r2, r3);
        if (ftab_out) ftab_out[(size_t)n * QUARTER + l] = pack_bf16x4(r0, r1, r2, r3);
    } else {
        r0 = r1 = r2 = r3 = 0.f;
    }

    // ---- epilogue: next layer's exp-score ----
    if (escore_out) {
        float nx = 0.f, ny = 0.f, nz = 0.f, nw = 0.f;
        if (l < QUARTER) {
            float4 v = ((const float4*)none_rel)[l];
            nx = v.x; ny = v.y; nz = v.z; nw = v.w;
        }
        float ss = half_reduce(nx * nx + ny * ny + nz * nz + nw * nw);
        float inv_nr = 1.f / fmaxf(sqrtf(ss), 1e-12f);
        float dot = half_reduce(r0 * nx + r1 * ny + r2 * nz + r3 * nw) * inv_nr;
        float sq  = half_reduce(r0 * r0 + r1 * r1 + r2 * r2 + r3 * r3);
        if (l == 0 && valid_n)
            escore_out[n] = __expf(-dot / fmaxf(sqrtf(sq), 1e-12f));
    }
}

// ---------------------------------------------------------------------------
extern "C" void kernel_launch(void* const* d_in, const int* in_sizes, int n_in,
                              void* d_out, int out_size, void* d_ws, size_t ws_size,
                              hipStream_t stream) {
    const float* features = (const float*)d_in[0];
    // d_in[1] = rel_emb: unused by the reference
    const int*   adj      = (const int*)d_in[2];
    const float* none_rel = (const float*)d_in[3];
    float* out = (float*)d_out;

    const int N = in_sizes[0] / D_FEAT;   // 50000
    const int E = in_sizes[2] / 2;        // 800000

    // ws layout (16B-aligned): start[N+1] | escore0[N] | escore1[N]
    //                          | ftab0[N*25 u64] | ftab1[N*25 u64]
    size_t off = 0;
    auto take = [&](size_t bytes) { size_t o = off; off = (off + bytes + 15) & ~(size_t)15; return o; };
    char* w = (char*)d_ws;
    int*   start   = (int*)  (w + take(sizeof(int)   * (size_t)(N + 1)));
    float* escore0 = (float*)(w + take(sizeof(float) * (size_t)N));
    float* escore1 = (float*)(w + take(sizeof(float) * (size_t)N));
    size_t ftab_off0 = take(sizeof(unsigned long long) * (size_t)N * QUARTER);
    size_t ftab_off1 = take(sizeof(unsigned long long) * (size_t)N * QUARTER);
    const bool use_bf16 = (ws_size >= off);
    unsigned long long* ftab0 = use_bf16 ? (unsigned long long*)(w + ftab_off0) : nullptr;
    unsigned long long* ftab1 = use_bf16 ? (unsigned long long*)(w + ftab_off1) : nullptr;

    const int pairs = (N + 1) / 2;                       // 2 nodes per wave
    const int node_blocks = (pairs * 64 + 255) / 256;
    const int2* adj2 = (const int2*)adj;

    tanh_score_kernel<<<node_blocks, 256, 0, stream>>>(features, out, ftab0,
                                                       escore0, none_rel, N);
    {
        int blocks = (N + 1 + 255) / 256;
        csr_kernel<<<blocks, 256, 0, stream>>>(adj, E, start, N);
    }
    if (use_bf16) {
        attn_kernel<true><<<node_blocks, 256, 0, stream>>>(
            ftab0, out + D_FEAT, ftab1, adj2, start, escore0, escore1, none_rel, N);
        attn_kernel<true><<<node_blocks, 256, 0, stream>>>(
            ftab1, out + 2 * D_FEAT, nullptr, adj2, start, escore1, nullptr, none_rel, N);
    } else {
        attn_kernel<false><<<node_blocks, 256, 0, stream>>>(
            out, out + D_FEAT, nullptr, adj2, start, escore0, escore1, none_rel, N);
        attn_kernel<false><<<node_blocks, 256, 0, stream>>>(
            out + D_FEAT, out + 2 * D_FEAT, nullptr, adj2, start, escore1, nullptr, none_rel, N);
    }
}

// Round 7
// 184.105 us; speedup vs baseline: 1.0553x; 1.0553x over previous
//
#include <hip/hip_runtime.h>
#include <math.h>

#define D_FEAT 100
#define QUARTER 25         // active lanes per 32-lane half: lane l holds elems 4l..4l+3
#define ROW_STRIDE 300     // 3 * D_FEAT concatenated output blocks

// ---------------------------------------------------------------------------
// fast tanh via hardware exp (safe: inputs bounded, |2x| <= ~12)
// ---------------------------------------------------------------------------
__device__ __forceinline__ float fast_tanh(float x) {
    float ax = fabsf(x);
    float e  = __expf(2.f * ax);
    float t  = 1.f - 2.f / (e + 1.f);
    return copysignf(t, x);
}

// ---------------------------------------------------------------------------
// bf16 packing (RNE)
// ---------------------------------------------------------------------------
__device__ __forceinline__ unsigned pack_bf16x2(float a, float b) {
    unsigned ua = __float_as_uint(a);
    unsigned ub = __float_as_uint(b);
    ua += 0x7fffu + ((ua >> 16) & 1u);
    ub += 0x7fffu + ((ub >> 16) & 1u);
    return (ua >> 16) | (ub & 0xffff0000u);
}
__device__ __forceinline__ unsigned long long pack_bf16x4(float a, float b,
                                                          float c, float d) {
    return (unsigned long long)pack_bf16x2(a, b) |
           ((unsigned long long)pack_bf16x2(c, d) << 32);
}

// gather 4 feature elements of `col` (bf16x4 packed table or f32 stride-300)
template <bool BF16>
__device__ __forceinline__ void gather4(const void* __restrict__ prev, int col,
                                        int l, bool act,
                                        float& x0, float& x1, float& x2, float& x3) {
    x0 = x1 = x2 = x3 = 0.f;
    if (!act) return;
    if (BF16) {
        unsigned long long u =
            ((const unsigned long long*)prev)[(size_t)(unsigned)(col * QUARTER + l)];
        unsigned lo = (unsigned)u, hi = (unsigned)(u >> 32);
        x0 = __uint_as_float(lo << 16);
        x1 = __uint_as_float(lo & 0xffff0000u);
        x2 = __uint_as_float(hi << 16);
        x3 = __uint_as_float(hi & 0xffff0000u);
    } else {
        float4 v = ((const float4*)((const float*)prev + (size_t)col * ROW_STRIDE))[l];
        x0 = v.x; x1 = v.y; x2 = v.z; x3 = v.w;
    }
}

// butterfly sum within each 32-lane half
__device__ __forceinline__ float half_reduce(float v) {
    #pragma unroll
    for (int off = 16; off; off >>= 1) v += __shfl_xor(v, off, 64);
    return v;
}

// ---------------------------------------------------------------------------
// Kernel 1: 2 nodes per wave (one per half) + fused CSR binary search.
// ---------------------------------------------------------------------------
__global__ __launch_bounds__(256) void tanh_score_kernel(
    const float* __restrict__ features,
    float* __restrict__ out,
    unsigned long long* __restrict__ ftab0,
    float* __restrict__ escore0,
    const float* __restrict__ none_rel,
    const int* __restrict__ adj,
    int* __restrict__ startArr,
    int E, int N)
{
    int gtid = blockIdx.x * blockDim.x + threadIdx.x;

    // fused CSR: first N+1 threads binary-search their row start
    if (gtid <= N) {
        if (gtid == N) startArr[N] = E;
        else {
            int lo = 0, hi = E;
            while (lo < hi) {
                int mid = (lo + hi) >> 1;
                if (adj[2 * mid] < gtid) lo = mid + 1; else hi = mid;
            }
            startArr[gtid] = lo;
        }
    }

    int waveId = gtid >> 6;
    int lane = threadIdx.x & 63;
    int half = lane >> 5;
    int l    = lane & 31;
    int n    = waveId * 2 + half;
    const bool valid_n = (n < N);
    const bool act = valid_n && (l < QUARTER);

    float x0 = 0.f, x1 = 0.f, x2 = 0.f, x3 = 0.f;
    if (act) {
        float4 f = ((const float4*)(features + (size_t)n * D_FEAT))[l];
        x0 = fast_tanh(f.x); x1 = fast_tanh(f.y);
        x2 = fast_tanh(f.z); x3 = fast_tanh(f.w);
        ((float4*)(out + (size_t)n * ROW_STRIDE))[l] = make_float4(x0, x1, x2, x3);
        if (ftab0) ftab0[(size_t)n * QUARTER + l] = pack_bf16x4(x0, x1, x2, x3);
    }

    float nx = 0.f, ny = 0.f, nz = 0.f, nw = 0.f;
    if (l < QUARTER) {
        float4 v = ((const float4*)none_rel)[l];
        nx = v.x; ny = v.y; nz = v.z; nw = v.w;
    }
    float ss = half_reduce(nx * nx + ny * ny + nz * nz + nw * nw);
    float inv_nr = 1.f / fmaxf(sqrtf(ss), 1e-12f);

    float dot = half_reduce(x0 * nx + x1 * ny + x2 * nz + x3 * nw) * inv_nr;
    float sq  = half_reduce(x0 * x0 + x1 * x1 + x2 * x2 + x3 * x3);
    if (l == 0 && valid_n)
        escore0[n] = __expf(-dot / fmaxf(sqrtf(sq), 1e-12f));
}

// ---------------------------------------------------------------------------
// Kernel 2: fused attention layer, 2 nodes per wave.
//  Stage up to 64 (col,w) per node in 2 register slots (2-level load chain),
//  then immediately aggregate in shfl-broadcast rounds of 8 — 8 independent
//  gathers in flight per wave. Denominator reduce AFTER the gather loop.
//  Per-half predication (i < deg): no padded fetches.
// ---------------------------------------------------------------------------
template <bool BF16>
__global__ __launch_bounds__(256) void attn_kernel(
    const void* __restrict__ prev,
    float* __restrict__ outp,
    unsigned long long* __restrict__ ftab_out,
    const int2* __restrict__ adj2,
    const int* __restrict__ start,
    const float* __restrict__ escore_in,
    float* __restrict__ escore_out,
    const float* __restrict__ none_rel,
    int N)
{
    int waveId = (int)((blockIdx.x * blockDim.x + threadIdx.x) >> 6);
    int lane = threadIdx.x & 63;
    int half = lane >> 5;
    int l    = lane & 31;
    int n    = waveId * 2 + half;
    const bool valid_n = (n < N);
    const bool act = valid_n && (l < QUARTER);
    const int base = half << 5;

    int e0 = 0, e1 = 0;
    if (valid_n) { e0 = start[n]; e1 = start[n + 1]; }
    const int deg = e1 - e0;

    // ---- stage (col, w): slots l (edges 0..31) and l+32 (edges 32..63) ----
    int   c0 = 0, c1 = 0;
    float w0 = 0.f, w1 = 0.f;
    if (l < deg)      { c0 = adj2[e0 + l].y;      w0 = escore_in[c0]; }
    if (l + 32 < deg) { c1 = adj2[e0 + l + 32].y; w1 = escore_in[c1]; }

    // wave-uniform trip bound
    int maxdeg = deg;
    { int o = __shfl_xor(maxdeg, 32, 64); maxdeg = maxdeg > o ? maxdeg : o; }

    // ---- aggregation: rounds of 8, per-half predicated ----
    float a0 = 0.f, a1 = 0.f, a2 = 0.f, a3 = 0.f;
    const int cap1 = maxdeg < 32 ? maxdeg : 32;
    for (int r = 0; r < cap1; r += 8) {
        #pragma unroll
        for (int j = 0; j < 8; ++j) {
            int   i = r + j;
            int   c = __shfl(c0, base + i, 64);
            float w = __shfl(w0, base + i, 64);
            float p0, p1, p2, p3;
            gather4<BF16>(prev, c, l, act && (i < deg), p0, p1, p2, p3);
            a0 += w * p0; a1 += w * p1; a2 += w * p2; a3 += w * p3;
        }
    }
    const int cap2 = maxdeg < 64 ? maxdeg : 64;
    for (int r = 32; r < cap2; r += 8) {
        #pragma unroll
        for (int j = 0; j < 8; ++j) {
            int   i = r + j;
            int   c = __shfl(c1, base + i - 32, 64);
            float w = __shfl(w1, base + i - 32, 64);
            float p0, p1, p2, p3;
            gather4<BF16>(prev, c, l, act && (i < deg), p0, p1, p2, p3);
            a0 += w * p0; a1 += w * p1; a2 += w * p2; a3 += w * p3;
        }
    }
    for (int e = e0 + 64; e < e1; ++e) {           // deg > 64: ~never
        int   c = adj2[e].y;
        float w = escore_in[c];
        float p0, p1, p2, p3;
        gather4<BF16>(prev, c, l, act, p0, p1, p2, p3);
        a0 += w * p0; a1 += w * p1; a2 += w * p2; a3 += w * p3;
    }

    // ---- denominator (off the gather critical path) ----
    float d_l = w0 + w1;
    for (int e = e0 + 64 + l; e < e1; e += 32) d_l += escore_in[adj2[e].y];
    d_l = half_reduce(d_l);
    const float inv_d = (deg > 0) ? 1.f / d_l : 0.f;

    float r0 = fast_tanh(a0 * inv_d);
    float r1 = fast_tanh(a1 * inv_d);
    float r2 = fast_tanh(a2 * inv_d);
    float r3 = fast_tanh(a3 * inv_d);
    if (act) {
        ((float4*)(outp + (size_t)n * ROW_STRIDE))[l] = make_float4(r0, r1, r2, r3);
        if (ftab_out) ftab_out[(size_t)n * QUARTER + l] = pack_bf16x4(r0, r1, r2, r3);
    } else {
        r0 = r1 = r2 = r3 = 0.f;
    }

    // ---- epilogue: next layer's exp-score ----
    if (escore_out) {
        float nx = 0.f, ny = 0.f, nz = 0.f, nw = 0.f;
        if (l < QUARTER) {
            float4 v = ((const float4*)none_rel)[l];
            nx = v.x; ny = v.y; nz = v.z; nw = v.w;
        }
        float ss = half_reduce(nx * nx + ny * ny + nz * nz + nw * nw);
        float inv_nr = 1.f / fmaxf(sqrtf(ss), 1e-12f);
        float dot = half_reduce(r0 * nx + r1 * ny + r2 * nz + r3 * nw) * inv_nr;
        float sq  = half_reduce(r0 * r0 + r1 * r1 + r2 * r2 + r3 * r3);
        if (l == 0 && valid_n)
            escore_out[n] = __expf(-dot / fmaxf(sqrtf(sq), 1e-12f));
    }
}

// ---------------------------------------------------------------------------
extern "C" void kernel_launch(void* const* d_in, const int* in_sizes, int n_in,
                              void* d_out, int out_size, void* d_ws, size_t ws_size,
                              hipStream_t stream) {
    const float* features = (const float*)d_in[0];
    // d_in[1] = rel_emb: unused by the reference
    const int*   adj      = (const int*)d_in[2];
    const float* none_rel = (const float*)d_in[3];
    float* out = (float*)d_out;

    const int N = in_sizes[0] / D_FEAT;   // 50000
    const int E = in_sizes[2] / 2;        // 800000

    // ws layout (16B-aligned): start[N+1] | escore0[N] | escore1[N]
    //                          | ftab0[N*25 u64] | ftab1[N*25 u64]
    size_t off = 0;
    auto take = [&](size_t bytes) { size_t o = off; off = (off + bytes + 15) & ~(size_t)15; return o; };
    char* w = (char*)d_ws;
    int*   start   = (int*)  (w + take(sizeof(int)   * (size_t)(N + 1)));
    float* escore0 = (float*)(w + take(sizeof(float) * (size_t)N));
    float* escore1 = (float*)(w + take(sizeof(float) * (size_t)N));
    size_t ftab_off0 = take(sizeof(unsigned long long) * (size_t)N * QUARTER);
    size_t ftab_off1 = take(sizeof(unsigned long long) * (size_t)N * QUARTER);
    const bool use_bf16 = (ws_size >= off);
    unsigned long long* ftab0 = use_bf16 ? (unsigned long long*)(w + ftab_off0) : nullptr;
    unsigned long long* ftab1 = use_bf16 ? (unsigned long long*)(w + ftab_off1) : nullptr;

    const int pairs = (N + 1) / 2;                       // 2 nodes per wave
    const int node_blocks = (pairs * 64 + 255) / 256;
    const int2* adj2 = (const int2*)adj;

    tanh_score_kernel<<<node_blocks, 256, 0, stream>>>(features, out, ftab0,
                                                       escore0, none_rel,
                                                       adj, start, E, N);
    if (use_bf16) {
        attn_kernel<true><<<node_blocks, 256, 0, stream>>>(
            ftab0, out + D_FEAT, ftab1, adj2, start, escore0, escore1, none_rel, N);
        attn_kernel<true><<<node_blocks, 256, 0, stream>>>(
            ftab1, out + 2 * D_FEAT, nullptr, adj2, start, escore1, nullptr, none_rel, N);
    } else {
        attn_kernel<false><<<node_blocks, 256, 0, stream>>>(
            out, out + D_FEAT, nullptr, adj2, start, escore0, escore1, none_rel, N);
        attn_kernel<false><<<node_blocks, 256, 0, stream>>>(
            out + D_FEAT, out + 2 * D_FEAT, nullptr, adj2, start, escore1, nullptr, none_rel, N);
    }
}

// Round 8
// 175.466 us; speedup vs baseline: 1.1073x; 1.0492x over previous
//
#include <hip/hip_runtime.h>
#include <math.h>

#define D_FEAT 100
#define ROW_STRIDE 300     // 3 * D_FEAT concatenated output blocks
#define ROWQ 26            // table row = 26 qwords = 208 B:
                           //   qword 0 = {w:f32, 0.f}; qwords 1..25 = bf16x4 feats
                           // 208-B rows always span exactly 4 cache lines.

// ---------------------------------------------------------------------------
// fast tanh via hardware exp (inputs bounded, |2x| <= ~12)
// ---------------------------------------------------------------------------
__device__ __forceinline__ float fast_tanh(float x) {
    float ax = fabsf(x);
    float e  = __expf(2.f * ax);
    float t  = 1.f - 2.f / (e + 1.f);
    return copysignf(t, x);
}

// bf16 packing (RNE)
__device__ __forceinline__ unsigned pack_bf16x2(float a, float b) {
    unsigned ua = __float_as_uint(a);
    unsigned ub = __float_as_uint(b);
    ua += 0x7fffu + ((ua >> 16) & 1u);
    ub += 0x7fffu + ((ub >> 16) & 1u);
    return (ua >> 16) | (ub & 0xffff0000u);
}
__device__ __forceinline__ unsigned long long pack_bf16x4(float a, float b,
                                                          float c, float d) {
    return (unsigned long long)pack_bf16x2(a, b) |
           ((unsigned long long)pack_bf16x2(c, d) << 32);
}
__device__ __forceinline__ void unpack_bf16x4(unsigned long long u,
                                              float& x0, float& x1,
                                              float& x2, float& x3) {
    unsigned lo = (unsigned)u, hi = (unsigned)(u >> 32);
    x0 = __uint_as_float(lo << 16);
    x1 = __uint_as_float(lo & 0xffff0000u);
    x2 = __uint_as_float(hi << 16);
    x3 = __uint_as_float(hi & 0xffff0000u);
}

// butterfly sum within each 32-lane half
__device__ __forceinline__ float half_reduce(float v) {
    #pragma unroll
    for (int off = 16; off; off >>= 1) v += __shfl_xor(v, off, 64);
    return v;
}

// ---------------------------------------------------------------------------
// Kernel 1: 2 nodes per wave + fused CSR binary search.
// Lane convention (shifted): lanes 1..25 hold elems 4(l-1)..4(l-1)+3.
// ---------------------------------------------------------------------------
__global__ __launch_bounds__(256) void tanh_score_kernel(
    const float* __restrict__ features,
    float* __restrict__ out,
    unsigned long long* __restrict__ tab0,   // 208-B-row table or null
    float* __restrict__ escore0,             // fallback score array
    const float* __restrict__ none_rel,
    const int* __restrict__ adj,
    int* __restrict__ startArr,
    int E, int N)
{
    int gtid = blockIdx.x * blockDim.x + threadIdx.x;
    if (gtid <= N) {                          // fused CSR
        if (gtid == N) startArr[N] = E;
        else {
            int lo = 0, hi = E;
            while (lo < hi) {
                int mid = (lo + hi) >> 1;
                if (adj[2 * mid] < gtid) lo = mid + 1; else hi = mid;
            }
            startArr[gtid] = lo;
        }
    }

    int waveId = gtid >> 6;
    int lane = threadIdx.x & 63;
    int half = lane >> 5;
    int l    = lane & 31;
    int n    = waveId * 2 + half;
    const bool valid_n = (n < N);
    const bool fact = valid_n && (l >= 1) && (l <= 25);

    float x0 = 0.f, x1 = 0.f, x2 = 0.f, x3 = 0.f;
    if (fact) {
        float4 f = ((const float4*)(features + (size_t)n * D_FEAT))[l - 1];
        x0 = fast_tanh(f.x); x1 = fast_tanh(f.y);
        x2 = fast_tanh(f.z); x3 = fast_tanh(f.w);
        ((float4*)(out + (size_t)n * ROW_STRIDE))[l - 1] = make_float4(x0, x1, x2, x3);
        if (tab0) tab0[(size_t)n * ROWQ + l] = pack_bf16x4(x0, x1, x2, x3);
    }

    float nx = 0.f, ny = 0.f, nz = 0.f, nw = 0.f;
    if (l >= 1 && l <= 25) {
        float4 v = ((const float4*)none_rel)[l - 1];
        nx = v.x; ny = v.y; nz = v.z; nw = v.w;
    }
    float ss = half_reduce(nx * nx + ny * ny + nz * nz + nw * nw);
    float inv_nr = 1.f / fmaxf(sqrtf(ss), 1e-12f);

    float dot = half_reduce(x0 * nx + x1 * ny + x2 * nz + x3 * nw) * inv_nr;
    float sq  = half_reduce(x0 * x0 + x1 * x1 + x2 * x2 + x3 * x3);
    if (l == 0 && valid_n) {
        float es = __expf(-dot / fmaxf(sqrtf(sq), 1e-12f));
        if (tab0) tab0[(size_t)n * ROWQ] = (unsigned long long)__float_as_uint(es);
        else      escore0[n] = es;
    }
}

// ---------------------------------------------------------------------------
// Kernel 2: fused attention layer, 2 nodes per wave.
//  TAB path: one 8-B load per lane per edge from the 208-B row delivers
//  features (lanes 1..25) AND the weight (lane 0) — 4 lines/edge, no escore
//  gather, no denominator pre-pass (denom accumulates from broadcast w).
// ---------------------------------------------------------------------------
template <bool TAB>
__global__ __launch_bounds__(256) void attn_kernel(
    const void* __restrict__ prev,           // TAB ? u64 table : f32 stride-300
    float* __restrict__ outp,
    unsigned long long* __restrict__ tab_out,
    const int2* __restrict__ adj2,
    const int* __restrict__ start,
    const float* __restrict__ escore_in,     // fallback only
    float* __restrict__ escore_out,          // fallback only
    const float* __restrict__ none_rel,
    int N)
{
    int waveId = (int)((blockIdx.x * blockDim.x + threadIdx.x) >> 6);
    int lane = threadIdx.x & 63;
    int half = lane >> 5;
    int l    = lane & 31;
    int n    = waveId * 2 + half;
    const bool valid_n = (n < N);
    const bool fact = valid_n && (l >= 1) && (l <= 25);
    const int base = half << 5;

    int e0 = 0, e1 = 0;
    if (valid_n) { e0 = start[n]; e1 = start[n + 1]; }
    const int deg = e1 - e0;

    // ---- stage cols (and weights in fallback) ----
    int   c0 = 0, c1 = 0;
    float w0 = 0.f, w1 = 0.f;
    if (l < deg)      { c0 = adj2[e0 + l].y;      if (!TAB) w0 = escore_in[c0]; }
    if (l + 32 < deg) { c1 = adj2[e0 + l + 32].y; if (!TAB) w1 = escore_in[c1]; }

    int maxdeg = deg;
    { int o = __shfl_xor(maxdeg, 32, 64); maxdeg = maxdeg > o ? maxdeg : o; }

    const unsigned long long* tab = (const unsigned long long*)prev;
    const float* pf32 = (const float*)prev;

    float d_acc = 0.f, a0 = 0.f, a1 = 0.f, a2 = 0.f, a3 = 0.f;
    const int cap1 = maxdeg < 32 ? maxdeg : 32;
    for (int r = 0; r < cap1; r += 8) {
        #pragma unroll
        for (int j = 0; j < 8; ++j) {
            int   i = r + j;
            int   c = __shfl(c0, base + i, 64);
            float w, p0, p1, p2, p3;
            if (TAB) {
                bool on = valid_n && (i < deg) && (l <= 25);
                unsigned long long v = 0;
                if (on) v = tab[(size_t)(unsigned)(c * ROWQ + l)];
                w = __shfl(__uint_as_float((unsigned)v), base, 64);
                unpack_bf16x4(v, p0, p1, p2, p3);
            } else {
                w = __shfl(w0, base + i, 64);
                p0 = p1 = p2 = p3 = 0.f;
                if (fact && (i < deg)) {
                    float4 v = ((const float4*)(pf32 + (size_t)c * ROW_STRIDE))[l - 1];
                    p0 = v.x; p1 = v.y; p2 = v.z; p3 = v.w;
                }
            }
            d_acc += w;
            a0 += w * p0; a1 += w * p1; a2 += w * p2; a3 += w * p3;
        }
    }
    const int cap2 = maxdeg < 64 ? maxdeg : 64;
    for (int r = 32; r < cap2; r += 8) {
        #pragma unroll
        for (int j = 0; j < 8; ++j) {
            int   i = r + j;
            int   c = __shfl(c1, base + i - 32, 64);
            float w, p0, p1, p2, p3;
            if (TAB) {
                bool on = valid_n && (i < deg) && (l <= 25);
                unsigned long long v = 0;
                if (on) v = tab[(size_t)(unsigned)(c * ROWQ + l)];
                w = __shfl(__uint_as_float((unsigned)v), base, 64);
                unpack_bf16x4(v, p0, p1, p2, p3);
            } else {
                w = __shfl(w1, base + i - 32, 64);
                p0 = p1 = p2 = p3 = 0.f;
                if (fact && (i < deg)) {
                    float4 v = ((const float4*)(pf32 + (size_t)c * ROW_STRIDE))[l - 1];
                    p0 = v.x; p1 = v.y; p2 = v.z; p3 = v.w;
                }
            }
            d_acc += w;
            a0 += w * p0; a1 += w * p1; a2 += w * p2; a3 += w * p3;
        }
    }
    for (int e = e0 + 64; e < e1; ++e) {      // deg > 64: ~never
        int c = adj2[e].y;
        float w, p0, p1, p2, p3;
        if (TAB) {
            unsigned long long v = 0;
            if (l <= 25) v = tab[(size_t)(unsigned)(c * ROWQ + l)];
            w = __shfl(__uint_as_float((unsigned)v), base, 64);
            unpack_bf16x4(v, p0, p1, p2, p3);
        } else {
            w = escore_in[c];
            p0 = p1 = p2 = p3 = 0.f;
            if (fact) {
                float4 v = ((const float4*)(pf32 + (size_t)c * ROW_STRIDE))[l - 1];
                p0 = v.x; p1 = v.y; p2 = v.z; p3 = v.w;
            }
        }
        d_acc += w;
        a0 += w * p0; a1 += w * p1; a2 += w * p2; a3 += w * p3;
    }

    const float inv_d = (deg > 0) ? 1.f / d_acc : 0.f;
    float r0 = fast_tanh(a0 * inv_d);
    float r1 = fast_tanh(a1 * inv_d);
    float r2 = fast_tanh(a2 * inv_d);
    float r3 = fast_tanh(a3 * inv_d);
    if (fact) {
        ((float4*)(outp + (size_t)n * ROW_STRIDE))[l - 1] = make_float4(r0, r1, r2, r3);
        if (TAB && tab_out)
            tab_out[(size_t)n * ROWQ + l] = pack_bf16x4(r0, r1, r2, r3);
    } else {
        r0 = r1 = r2 = r3 = 0.f;
    }

    // ---- epilogue: next layer's exp-score (into table qword 0) ----
    if (tab_out || escore_out) {
        float nx = 0.f, ny = 0.f, nz = 0.f, nw = 0.f;
        if (l >= 1 && l <= 25) {
            float4 v = ((const float4*)none_rel)[l - 1];
            nx = v.x; ny = v.y; nz = v.z; nw = v.w;
        }
        float ss = half_reduce(nx * nx + ny * ny + nz * nz + nw * nw);
        float inv_nr = 1.f / fmaxf(sqrtf(ss), 1e-12f);
        float dot = half_reduce(r0 * nx + r1 * ny + r2 * nz + r3 * nw) * inv_nr;
        float sq  = half_reduce(r0 * r0 + r1 * r1 + r2 * r2 + r3 * r3);
        if (l == 0 && valid_n) {
            float es = __expf(-dot / fmaxf(sqrtf(sq), 1e-12f));
            if (TAB) tab_out[(size_t)n * ROWQ] = (unsigned long long)__float_as_uint(es);
            else     escore_out[n] = es;
        }
    }
}

// ---------------------------------------------------------------------------
extern "C" void kernel_launch(void* const* d_in, const int* in_sizes, int n_in,
                              void* d_out, int out_size, void* d_ws, size_t ws_size,
                              hipStream_t stream) {
    const float* features = (const float*)d_in[0];
    // d_in[1] = rel_emb: unused by the reference
    const int*   adj      = (const int*)d_in[2];
    const float* none_rel = (const float*)d_in[3];
    float* out = (float*)d_out;

    const int N = in_sizes[0] / D_FEAT;   // 50000
    const int E = in_sizes[2] / 2;        // 800000

    // ws: start[N+1] | escore0[N] | escore1[N] | tab0[N*26 u64] | tab1[N*26 u64]
    size_t off = 0;
    auto take = [&](size_t bytes) { size_t o = off; off = (off + bytes + 15) & ~(size_t)15; return o; };
    char* w = (char*)d_ws;
    int*   start   = (int*)  (w + take(sizeof(int)   * (size_t)(N + 1)));
    float* escore0 = (float*)(w + take(sizeof(float) * (size_t)N));
    float* escore1 = (float*)(w + take(sizeof(float) * (size_t)N));
    size_t tab_off0 = take(sizeof(unsigned long long) * (size_t)N * ROWQ);
    size_t tab_off1 = take(sizeof(unsigned long long) * (size_t)N * ROWQ);
    const bool use_tab = (ws_size >= off);
    unsigned long long* tab0 = use_tab ? (unsigned long long*)(w + tab_off0) : nullptr;
    unsigned long long* tab1 = use_tab ? (unsigned long long*)(w + tab_off1) : nullptr;

    const int pairs = (N + 1) / 2;                       // 2 nodes per wave
    const int node_blocks = (pairs * 64 + 255) / 256;
    const int2* adj2 = (const int2*)adj;

    tanh_score_kernel<<<node_blocks, 256, 0, stream>>>(features, out, tab0,
                                                       escore0, none_rel,
                                                       adj, start, E, N);
    if (use_tab) {
        attn_kernel<true><<<node_blocks, 256, 0, stream>>>(
            tab0, out + D_FEAT, tab1, adj2, start, nullptr, nullptr, none_rel, N);
        attn_kernel<true><<<node_blocks, 256, 0, stream>>>(
            tab1, out + 2 * D_FEAT, nullptr, adj2, start, nullptr, nullptr, none_rel, N);
    } else {
        attn_kernel<false><<<node_blocks, 256, 0, stream>>>(
            out, out + D_FEAT, nullptr, adj2, start, escore0, escore1, none_rel, N);
        attn_kernel<false><<<node_blocks, 256, 0, stream>>>(
            out + D_FEAT, out + 2 * D_FEAT, nullptr, adj2, start, escore1, nullptr, none_rel, N);
    }
}